// Round 9
// baseline (136.896 us; speedup 1.0000x reference)
//
#include <hip/hip_runtime.h>
#include <hip/hip_bf16.h>

#define HEADS 8
#define HID   64
#define EMB   512
#define HH    512
#define LOCAL 64
#define BS    4
#define NSEQ  2048
#define ROWS  (BS*NSEQ)   // 8192

typedef __attribute__((ext_vector_type(8))) short short8;   // 8 bf16 = 4 VGPRs
typedef __attribute__((ext_vector_type(4))) float f32x4;

__device__ __forceinline__ ushort f2b(float f) {
    union { float f; unsigned u; } c; c.f = f;
    return (ushort)((c.u + 0x7FFFu + ((c.u >> 16) & 1u)) >> 16);
}
__device__ __forceinline__ float b2f(ushort u) {
    union { unsigned u; float f; } c; c.u = ((unsigned)u) << 16; return c.f;
}

__device__ __forceinline__ void async16(const void* g, void* l) {
    __builtin_amdgcn_global_load_lds(
        (const __attribute__((address_space(1))) void*)g,
        (__attribute__((address_space(3))) void*)l, 16, 0, 0);
}

#define MFMA16(a, b, c) __builtin_amdgcn_mfma_f32_16x16x32_bf16(a, b, c, 0, 0, 0)

// ---------------------------------------------------------------------------
// prep: blocks [0,4096) convert x -> bf16 (float4 in, ushort4 out).
// Blocks [4096,5120): transpose the four weight matrices to n-major bf16 via
// 64k x 16n tiles — float4 coalesced loads, LDS transpose (stride 65,
// conflict-free), short4 stores giving 128B per n-row (old 16x16 tiles did
// 2B scattered stores in 32B segments).
// ---------------------------------------------------------------------------
__global__ __launch_bounds__(256) void prep(
    const float* __restrict__ x,
    const float* __restrict__ w0, const float* __restrict__ w1,
    const float* __restrict__ w2, const float* __restrict__ w3,
    ushort* __restrict__ xb, ushort* __restrict__ dst012,
    ushort* __restrict__ dst3)
{
    __shared__ float sT[16][65];
    const int id = blockIdx.x;
    if (id < 4096) {
        const int i = id * 256 + threadIdx.x;
        float4 f = ((const float4*)x)[i];
        ushort4 u;
        u.x = f2b(f.x); u.y = f2b(f.y); u.z = f2b(f.z); u.w = f2b(f.w);
        ((ushort4*)xb)[i] = u;
    } else {
        const int id2 = id - 4096;                 // 0..1023
        const int z = id2 >> 8, t = id2 & 255;     // 256 tiles per matrix
        const float* src = (z == 0) ? w0 : (z == 1) ? w1 : (z == 2) ? w2 : w3;
        ushort* dst = (z < 3) ? dst012 + (size_t)z * 512 * 512 : dst3;
        const int k0 = (t >> 5) * 64, n0 = (t & 31) * 16;
        {
            const int ky = threadIdx.x & 63, nx = threadIdx.x >> 6;
            const float4 f = *(const float4*)&src[(size_t)(k0 + ky) * 512 + n0 + nx * 4];
            sT[nx * 4 + 0][ky] = f.x;
            sT[nx * 4 + 1][ky] = f.y;
            sT[nx * 4 + 2][ky] = f.z;
            sT[nx * 4 + 3][ky] = f.w;
        }
        __syncthreads();
        {
            const int nr = threadIdx.x >> 4, kx = (threadIdx.x & 15) * 4;
            ushort4 u;
            u.x = f2b(sT[nr][kx + 0]);
            u.y = f2b(sT[nr][kx + 1]);
            u.z = f2b(sT[nr][kx + 2]);
            u.w = f2b(sT[nr][kx + 3]);
            *(ushort4*)&dst[(size_t)(n0 + nr) * 512 + k0 + kx] = u;
        }
    }
}

// ---------------------------------------------------------------------------
// QKV GEMM: 128x128 tiles, BK=64 via two 32-k planes (m97 staging).
// Epilogue: LDS repack, 16B stores; q,k scaled 0.125; V also written in
// fragment-tiled layout vF[(b*8+h)][n/8][d][8].
// ---------------------------------------------------------------------------
__global__ __launch_bounds__(256) void gemm_qkv(
    const ushort* __restrict__ A, const ushort* __restrict__ Bt,
    ushort* __restrict__ oq, ushort* __restrict__ ok, ushort* __restrict__ ov,
    ushort* __restrict__ vT)
{
    __shared__ ushort Sbuf[4 * 128 * 32];   // As[2] | Bs[2]
    ushort* As = Sbuf;
    ushort* Bs = Sbuf + 2 * 128 * 32;
    const int tid  = threadIdx.x;
    const int rowB = (blockIdx.x & 63) * 128;
    const int colB = (blockIdx.x >> 6) * 128;
    const int wave = tid >> 6, lane = tid & 63;
    const int wm = wave & 1, wn = wave >> 1;
    const int l15 = lane & 15, quad = lane >> 4;

    f32x4 acc[4][4] = {};

    for (int kt = 0; kt < 512; kt += 64) {
#pragma unroll
        for (int pl = 0; pl < 2; ++pl)
#pragma unroll
            for (int p = 0; p < 2; ++p) {
                const int c = p * 256 + tid;
                const int row = c >> 2, sc = (c & 3) * 8;
                async16(A  + (size_t)(rowB + row) * 512 + kt + pl * 32 + sc,
                        &As[pl * 4096 + c * 8]);
                async16(Bt + (size_t)(colB + row) * 512 + kt + pl * 32 + sc,
                        &Bs[pl * 4096 + c * 8]);
            }
        __syncthreads();

#pragma unroll
        for (int pl = 0; pl < 2; ++pl) {
            short8 af[4], bf[4];
#pragma unroll
            for (int mi = 0; mi < 4; ++mi)
                af[mi] = *(const short8*)&As[pl * 4096 +
                          (wm * 64 + mi * 16 + l15) * 32 + quad * 8];
#pragma unroll
            for (int ni = 0; ni < 4; ++ni)
                bf[ni] = *(const short8*)&Bs[pl * 4096 +
                          (wn * 64 + ni * 16 + l15) * 32 + quad * 8];
#pragma unroll
            for (int mi = 0; mi < 4; ++mi)
#pragma unroll
                for (int ni = 0; ni < 4; ++ni)
                    acc[mi][ni] = MFMA16(af[mi], bf[ni], acc[mi][ni]);
        }
        __syncthreads();
    }
    // Sbuf dead -> per-wave repack regions.

    ushort* T = Sbuf + wave * 2048;      // 16 rows x stride 72
    const int sec = colB >> 9;           // block-uniform
    const float s = (sec == 2) ? 1.0f : 0.125f;
    const int cb = (colB & 511) + wn * 64;
#pragma unroll
    for (int mi = 0; mi < 4; ++mi) {
#pragma unroll
        for (int ni = 0; ni < 4; ++ni)
#pragma unroll
            for (int r = 0; r < 4; ++r)
                T[(quad * 4 + r) * 72 + ni * 16 + l15] = f2b(acc[mi][ni][r] * s);
        ushort* dst = (sec == 0) ? oq : (sec == 1) ? ok : ov;
#pragma unroll
        for (int u = 0; u < 2; ++u) {
            const int cid = lane * 2 + u;
            const int row = cid >> 3, ch = cid & 7;
            const int grow = rowB + wm * 64 + mi * 16 + row;
            *(short8*)&dst[(size_t)grow * HH + cb + ch * 8] =
                *(const short8*)&T[row * 72 + ch * 8];
        }
        if (sec == 2) {
            const int hh = cb >> 6;
            const int bb = rowB >> 11;
            const int nn0 = (rowB & 2047) + wm * 64 + mi * 16;
            // vF[(b*8+h)][n/8][d=lane][n%8]: coalesced 1KB wave stores.
            ushort* vbase = vT +
                (((size_t)(bb * HEADS + hh) * 256 + (nn0 >> 3)) * 64) * 8;
#pragma unroll
            for (int u = 0; u < 2; ++u) {
                short8 val;
#pragma unroll
                for (int j = 0; j < 8; ++j) val[j] = T[(u * 8 + j) * 72 + lane];
                *(short8*)(vbase + ((size_t)(u * 64 + lane)) * 8) = val;
            }
        }
    }
}

// ---------------------------------------------------------------------------
// Unify GEMM: 128x64 tiles, BK=64 two-plane staging.  +bias, fp32 out.
// ---------------------------------------------------------------------------
__global__ __launch_bounds__(256) void gemm_unify(
    const ushort* __restrict__ A, const ushort* __restrict__ Bt,
    const float* __restrict__ bias, float* __restrict__ out)
{
    __shared__ ushort Sbuf[2 * 128 * 32 + 2 * 64 * 32];   // As[2] | Bs[2]
    ushort* As = Sbuf;
    ushort* Bs = Sbuf + 2 * 128 * 32;
    const int tid  = threadIdx.x;
    const int rowB = (blockIdx.x & 63) * 128;
    const int colB = (blockIdx.x >> 6) * 64;
    const int wave = tid >> 6, lane = tid & 63;
    const int wm = wave & 1, wn = wave >> 1;
    const int l15 = lane & 15, quad = lane >> 4;

    f32x4 acc[4][2] = {};

    for (int kt = 0; kt < 512; kt += 64) {
#pragma unroll
        for (int pl = 0; pl < 2; ++pl) {
#pragma unroll
            for (int p = 0; p < 2; ++p) {
                const int c = p * 256 + tid;
                const int row = c >> 2, sc = (c & 3) * 8;
                async16(A + (size_t)(rowB + row) * 512 + kt + pl * 32 + sc,
                        &As[pl * 4096 + c * 8]);
            }
            {
                const int row = tid >> 2, sc = (tid & 3) * 8;
                async16(Bt + (size_t)(colB + row) * 512 + kt + pl * 32 + sc,
                        &Bs[pl * 2048 + tid * 8]);
            }
        }
        __syncthreads();

#pragma unroll
        for (int pl = 0; pl < 2; ++pl) {
            short8 af[4], bf[2];
#pragma unroll
            for (int mi = 0; mi < 4; ++mi)
                af[mi] = *(const short8*)&As[pl * 4096 +
                          (wm * 64 + mi * 16 + l15) * 32 + quad * 8];
#pragma unroll
            for (int ni = 0; ni < 2; ++ni)
                bf[ni] = *(const short8*)&Bs[pl * 2048 +
                          (wn * 32 + ni * 16 + l15) * 32 + quad * 8];
#pragma unroll
            for (int mi = 0; mi < 4; ++mi)
#pragma unroll
                for (int ni = 0; ni < 2; ++ni)
                    acc[mi][ni] = MFMA16(af[mi], bf[ni], acc[mi][ni]);
        }
        __syncthreads();
    }
    // Sbuf dead -> per-wave fp32 repack: 16 rows x stride 36 floats.

    float* Tf = (float*)Sbuf + wave * (16 * 36);
    float bcol[2];
#pragma unroll
    for (int ni = 0; ni < 2; ++ni)
        bcol[ni] = bias[colB + wn * 32 + ni * 16 + l15];
#pragma unroll
    for (int mi = 0; mi < 4; ++mi) {
#pragma unroll
        for (int ni = 0; ni < 2; ++ni)
#pragma unroll
            for (int r = 0; r < 4; ++r)
                Tf[(quad * 4 + r) * 36 + ni * 16 + l15] =
                    acc[mi][ni][r] + bcol[ni];
#pragma unroll
        for (int u = 0; u < 2; ++u) {
            const int cid = lane * 2 + u;
            const int row = cid >> 3, ch = cid & 7;
            *(float4*)&out[(size_t)(rowB + wm * 64 + mi * 16 + row) * EMB +
                           colB + wn * 32 + ch * 4] =
                *(const float4*)&Tf[row * 36 + ch * 4];
        }
    }
}

// ---------------------------------------------------------------------------
// Kernel B: strided attention in RESIDUE space.
// ---------------------------------------------------------------------------
__global__ __launch_bounds__(64) void attn_str(
    const ushort* __restrict__ q, const ushort* __restrict__ k,
    const ushort* __restrict__ v, ushort* __restrict__ obn,
    float* __restrict__ mbuf, float* __restrict__ sbuf)
{
    const int slice = blockIdx.x & 31;     // h + 8*b
    const int r     = blockIdx.x >> 5;     // residue 0..63
    const int h = slice & 7, b = slice >> 3;
    const int lane = threadIdx.x, l15 = lane & 15, quad = lane >> 4;
    const ptrdiff_t rowb = (ptrdiff_t)b * NSEQ;
    const int hb = h * HID;

    __shared__ union {
        struct { ushort Ps[32][40]; ushort Vt[64][40]; } s;
        float Ot[32][66];
    } U;

    {
        const int dg = lane & 7, g = lane >> 3;
#pragma unroll
        for (int p = 0; p < 4; ++p) {
            const int i = p * 8 + g;
            const short8 vv = *(const short8*)(
                v + (rowb + r + 64 * i) * 512 + hb + dg * 8);
#pragma unroll
            for (int e = 0; e < 8; ++e) {
                const int m = (e + dg) & 7;
                U.s.Vt[dg * 8 + m][i] = (ushort)vv[m];
            }
        }
    }
    { ushort4 z = {0, 0, 0, 0}; *(ushort4*)&U.s.Ps[l15][16 + quad * 4] = z; }

    short8 aq[2][2], bk[2][2];
#pragma unroll
    for (int t = 0; t < 2; ++t) {
        const ushort* p = q + (rowb + r + 64 * (t * 16 + l15)) * 512 + hb + quad * 8;
        aq[t][0] = *(const short8*)p;
        aq[t][1] = *(const short8*)(p + 32);
        const ushort* pk = k + (rowb + r + 64 * (t * 16 + l15)) * 512 + hb + quad * 8;
        bk[t][0] = *(const short8*)pk;
        bk[t][1] = *(const short8*)(pk + 32);
    }
    f32x4 s00 = {}, s10 = {}, s11 = {};
    s00 = MFMA16(aq[0][0], bk[0][0], s00); s00 = MFMA16(aq[0][1], bk[0][1], s00);
    s10 = MFMA16(aq[1][0], bk[0][0], s10); s10 = MFMA16(aq[1][1], bk[0][1], s10);
    s11 = MFMA16(aq[1][0], bk[1][0], s11); s11 = MFMA16(aq[1][1], bk[1][1], s11);

    float rsB[2][4];
#pragma unroll
    for (int t = 0; t < 2; ++t)
#pragma unroll
        for (int rg = 0; rg < 4; ++rg) {
            const int i = t * 16 + quad * 4 + rg;
            float v0 = (t == 0) ? s00[rg] : s10[rg];
            float v1 = (t == 1) ? s11[rg] : -1e30f;
            if (l15 > i - 2) v0 = -1e30f;
            if (t == 1 && 16 + l15 > i - 2) v1 = -1e30f;
            float mx = fmaxf(v0, v1);
            mx = fmaxf(mx, __shfl_xor(mx, 1)); mx = fmaxf(mx, __shfl_xor(mx, 2));
            mx = fmaxf(mx, __shfl_xor(mx, 4)); mx = fmaxf(mx, __shfl_xor(mx, 8));
            const float e0 = __expf(v0 - mx);
            const float e1 = (t == 1) ? __expf(v1 - mx) : 0.f;
            float sum = e0 + e1;
            sum += __shfl_xor(sum, 1); sum += __shfl_xor(sum, 2);
            sum += __shfl_xor(sum, 4); sum += __shfl_xor(sum, 8);
            U.s.Ps[i][l15] = f2b(e0);
            if (t == 1) U.s.Ps[i][16 + l15] = f2b(e1);
            rsB[t][rg] = 1.0f / sum;
            if (l15 == 0 && i >= 2) {
                mbuf[(size_t)slice * NSEQ + r + 64 * i] = mx;
                sbuf[(size_t)slice * NSEQ + r + 64 * i] = sum;
            }
        }

    short8 ap[2], bp[4];
#pragma unroll
    for (int t = 0; t < 2; ++t)
        ap[t] = *(const short8*)&U.s.Ps[t * 16 + l15][quad * 8];
#pragma unroll
    for (int nt = 0; nt < 4; ++nt)
        bp[nt] = *(const short8*)&U.s.Vt[nt * 16 + l15][quad * 8];
    f32x4 O[2][4] = {};
#pragma unroll
    for (int t = 0; t < 2; ++t)
#pragma unroll
        for (int nt = 0; nt < 4; ++nt)
            O[t][nt] = MFMA16(ap[t], bp[nt], O[t][nt]);

#pragma unroll
    for (int t = 0; t < 2; ++t)
#pragma unroll
        for (int nt = 0; nt < 4; ++nt)
#pragma unroll
            for (int rg = 0; rg < 4; ++rg)
                U.Ot[t * 16 + quad * 4 + rg][nt * 16 + l15] = O[t][nt][rg] * rsB[t][rg];
    for (int i = 2; i < 32; ++i)
        obn[(rowb + r + 64 * i) * 512 + hb + lane] = f2b(U.Ot[i][lane]);
}

// ---------------------------------------------------------------------------
// Kernel A: local-band attention + flash-merge, 32 queries/wave.
// Mask: single unsigned compare (col-i in [0,64]); the band0+col>=0 edge
// term only live for qw<64 (block-uniform branch).
// ---------------------------------------------------------------------------
struct __align__(16) WaveWS {
    union { ushort Ps[32][104]; float Ot[32][66]; } u;   // 104: 208B stride, 2-way
    float ca[32], cb[32];
};

__global__ __launch_bounds__(64) void attn_band(
    const ushort* __restrict__ q, const ushort* __restrict__ k,
    const ushort* __restrict__ vT, const ushort* __restrict__ obn,
    const float* __restrict__ mbuf, const float* __restrict__ sbuf,
    ushort* __restrict__ o)
{
    const int slice = blockIdx.x & 31;
    const int qidx  = blockIdx.x >> 5;
    const int h = slice & 7, b = slice >> 3;
    const int lane = threadIdx.x;
    const int l15 = lane & 15, quad = lane >> 4;
    const int qw = qidx * 32;
    const int band0 = qw - 64;
    const bool merge = (qw >= 128);
    const bool edge  = (qw < 64);

    __shared__ WaveWS S;
    const ptrdiff_t rowb = (ptrdiff_t)b * NSEQ;
    const int hb = h * HID;

    short8 afq[2][2];
#pragma unroll
    for (int t = 0; t < 2; ++t) {
        const ushort* qp = q + (rowb + qw + t * 16 + l15) * 512 + hb + quad * 8;
        afq[t][0] = *(const short8*)qp;
        afq[t][1] = *(const short8*)(qp + 32);
    }

    // QK^T over the 96-col band: t=0 uses cols [0,80), t=1 uses [16,96).
    f32x4 accA[5], accB[5];
#pragma unroll
    for (int i = 0; i < 5; ++i) {
        accA[i] = (f32x4){0.f, 0.f, 0.f, 0.f};
        accB[i] = (f32x4){0.f, 0.f, 0.f, 0.f};
    }
#pragma unroll
    for (int kt = 0; kt < 6; ++kt) {
        const ushort* kp = k + (rowb + band0 + kt * 16 + l15) * 512 + hb + quad * 8;
        const short8 b0 = *(const short8*)kp;
        const short8 b1 = *(const short8*)(kp + 32);
        if (kt < 5) {
            accA[kt] = MFMA16(afq[0][0], b0, accA[kt]);
            accA[kt] = MFMA16(afq[0][1], b1, accA[kt]);
        }
        if (kt > 0) {
            accB[kt - 1] = MFMA16(afq[1][0], b0, accB[kt - 1]);
            accB[kt - 1] = MFMA16(afq[1][1], b1, accB[kt - 1]);
        }
    }

#pragma unroll
    for (int t = 0; t < 2; ++t)
#pragma unroll
        for (int rg = 0; rg < 4; ++rg) {
            const int row16 = quad * 4 + rg;
            const int i = t * 16 + row16;
            float pm[6];
#pragma unroll
            for (int kt = 0; kt < 6; ++kt) {
                const int col = kt * 16 + l15;
                float val = -1e30f;
                if (t == 0) { if (kt < 5) val = accA[kt][rg]; }
                else        { if (kt > 0) val = accB[kt - 1][rg]; }
                bool okm = (unsigned)(col - i) <= 64u;       // col>=i && col<=i+64
                if (edge) okm = okm && (band0 + col >= 0);   // block-uniform
                pm[kt] = okm ? val : -1e30f;
            }
            float mx = fmaxf(fmaxf(fmaxf(pm[0], pm[1]), fmaxf(pm[2], pm[3])),
                             fmaxf(pm[4], pm[5]));
            mx = fmaxf(mx, __shfl_xor(mx, 1)); mx = fmaxf(mx, __shfl_xor(mx, 2));
            mx = fmaxf(mx, __shfl_xor(mx, 4)); mx = fmaxf(mx, __shfl_xor(mx, 8));
            float sum = 0.f;
#pragma unroll
            for (int kt = 0; kt < 6; ++kt) {
                const float pv = __expf(pm[kt] - mx);
                sum += pv;
                S.u.Ps[i][kt * 16 + l15] = f2b(pv);
            }
            sum += __shfl_xor(sum, 1); sum += __shfl_xor(sum, 2);
            sum += __shfl_xor(sum, 4); sum += __shfl_xor(sum, 8);
            if (l15 == 0) {
                if (merge) {
                    const float mB = mbuf[(size_t)slice * NSEQ + qw + i];
                    const float sB = sbuf[(size_t)slice * NSEQ + qw + i];
                    const float m  = fmaxf(mx, mB);
                    const float eA = __expf(mx - m), eB = __expf(mB - m);
                    const float denom = sum * eA + sB * eB;
                    S.ca[i] = eA / denom;
                    S.cb[i] = sB * eB / denom;
                } else {
                    S.ca[i] = 1.0f / sum;
                    S.cb[i] = 0.f;
                }
            }
        }

    f32x4 O[2][4] = {};
    const ushort* vtb = vT + (size_t)slice * (256 * 64 * 8);
#pragma unroll
    for (int ks = 0; ks < 3; ++ks) {
        const short8 ap0 = *(const short8*)&S.u.Ps[l15][ks * 32 + quad * 8];
        const short8 ap1 = *(const short8*)&S.u.Ps[16 + l15][ks * 32 + quad * 8];
        const int nb = (band0 >> 3) + ks * 4 + quad;   // may be negative: P==0 there
#pragma unroll
        for (int nt = 0; nt < 4; ++nt) {
            const short8 bp = *(const short8*)(
                vtb + ((ptrdiff_t)nb * 64 + nt * 16 + l15) * 8);
            O[0][nt] = MFMA16(ap0, bp, O[0][nt]);
            O[1][nt] = MFMA16(ap1, bp, O[1][nt]);
        }
    }

#pragma unroll
    for (int t = 0; t < 2; ++t)
#pragma unroll
        for (int nt = 0; nt < 4; ++nt)
#pragma unroll
            for (int rg = 0; rg < 4; ++rg)
                S.u.Ot[t * 16 + quad * 4 + rg][nt * 16 + l15] = O[t][nt][rg];

    if (merge) {
#pragma unroll 4
        for (int i2 = 0; i2 < 32; ++i2) {
            const ptrdiff_t off = (rowb + qw + i2) * 512 + hb + lane;
            const float val = S.u.Ot[i2][lane] * S.ca[i2] + b2f(obn[off]) * S.cb[i2];
            o[off] = f2b(val);
        }
    } else {
#pragma unroll 4
        for (int i2 = 0; i2 < 32; ++i2) {
            const ptrdiff_t off = (rowb + qw + i2) * 512 + hb + lane;
            o[off] = f2b(S.u.Ot[i2][lane] * S.ca[i2]);
        }
    }
}

// ---------------------------------------------------------------------------
extern "C" void kernel_launch(void* const* d_in, const int* in_sizes, int n_in,
                              void* d_out, int out_size, void* d_ws, size_t ws_size,
                              hipStream_t stream)
{
    // dict order: x, w_keys, w_queries, w_values, w_unify, b_unify (fp32)
    const float* x  = (const float*)d_in[0];
    const float* wk = (const float*)d_in[1];
    const float* wq = (const float*)d_in[2];
    const float* wv = (const float*)d_in[3];
    const float* wu = (const float*)d_in[4];
    const float* bu = (const float*)d_in[5];
    float* out = (float*)d_out;

    // ws: xb 8M | wbt 1.5M | wubt .5M | ob 8M | qb 8M | kb 8M | vF 8M | vb 8M
    //     | obn 8M | mbuf .25M | sbuf .25M
    ushort* xb   = (ushort*)d_ws;
    ushort* wbt  = xb   + (size_t)ROWS * EMB;
    ushort* wubt = wbt  + (size_t)1536 * 512;
    ushort* ob   = wubt + (size_t)512 * 512;
    ushort* qbuf = ob   + (size_t)ROWS * HH;
    ushort* kbuf = qbuf + (size_t)ROWS * HH;
    ushort* vTb  = kbuf + (size_t)ROWS * HH;
    ushort* vbuf = vTb  + (size_t)ROWS * HH;
    ushort* obn  = vbuf + (size_t)ROWS * HH;
    float*  mbuf = (float*)(obn + (size_t)ROWS * HH);
    float*  sbuf = mbuf + (size_t)32 * NSEQ;

    prep<<<4096 + 1024, 256, 0, stream>>>(x, wq, wk, wv, wu, xb, wbt, wubt);
    gemm_qkv<<<12 * 64, 256, 0, stream>>>(xb, wbt, qbuf, kbuf, vbuf, vTb);
    attn_str<<<64 * 32, 64, 0, stream>>>(qbuf, kbuf, vbuf, obn, mbuf, sbuf);
    attn_band<<<64 * 32, 64, 0, stream>>>(qbuf, kbuf, vTb, obn, mbuf, sbuf, ob);
    gemm_unify<<<8 * 64, 256, 0, stream>>>(ob, wubt, bu, out);
}

// Round 10
// 135.281 us; speedup vs baseline: 1.0119x; 1.0119x over previous
//
#include <hip/hip_runtime.h>
#include <hip/hip_bf16.h>

#define HEADS 8
#define HID   64
#define EMB   512
#define HH    512
#define LOCAL 64
#define BS    4
#define NSEQ  2048
#define ROWS  (BS*NSEQ)   // 8192

typedef __attribute__((ext_vector_type(8))) short short8;   // 8 bf16 = 4 VGPRs
typedef __attribute__((ext_vector_type(4))) float f32x4;

__device__ __forceinline__ ushort f2b(float f) {
    union { float f; unsigned u; } c; c.f = f;
    return (ushort)((c.u + 0x7FFFu + ((c.u >> 16) & 1u)) >> 16);
}
__device__ __forceinline__ float b2f(ushort u) {
    union { unsigned u; float f; } c; c.u = ((unsigned)u) << 16; return c.f;
}

__device__ __forceinline__ void async16(const void* g, void* l) {
    __builtin_amdgcn_global_load_lds(
        (const __attribute__((address_space(1))) void*)g,
        (__attribute__((address_space(3))) void*)l, 16, 0, 0);
}

#define MFMA16(a, b, c) __builtin_amdgcn_mfma_f32_16x16x32_bf16(a, b, c, 0, 0, 0)

// ---------------------------------------------------------------------------
// prep: blocks [0,4096) convert x -> bf16; blocks [4096,8192) transpose the
// four weight matrices to n-major bf16.  (R8 version — R9's 64x16 retile was
// neutral-to-negative, reverted.)
// ---------------------------------------------------------------------------
__global__ __launch_bounds__(256) void prep(
    const float* __restrict__ x,
    const float* __restrict__ w0, const float* __restrict__ w1,
    const float* __restrict__ w2, const float* __restrict__ w3,
    ushort* __restrict__ xb, ushort* __restrict__ dst012,
    ushort* __restrict__ dst3)
{
    __shared__ float s[16][17];
    const int id = blockIdx.x;
    if (id < 4096) {
        const int i = id * 256 + threadIdx.x;
        float4 f = ((const float4*)x)[i];
        ushort4 u;
        u.x = f2b(f.x); u.y = f2b(f.y); u.z = f2b(f.z); u.w = f2b(f.w);
        ((ushort4*)xb)[i] = u;
    } else {
        const int id2 = id - 4096;
        const int z = id2 >> 10, t = id2 & 1023;
        const float* src = (z == 0) ? w0 : (z == 1) ? w1 : (z == 2) ? w2 : w3;
        ushort* dst = (z < 3) ? dst012 + (size_t)z * 512 * 512 : dst3;
        const int n0 = (t & 31) * 16, k0 = (t >> 5) * 16;
        const int tx = threadIdx.x & 15, ty = threadIdx.x >> 4;
        s[ty][tx] = src[(size_t)(k0 + ty) * 512 + n0 + tx];
        __syncthreads();
        dst[(size_t)(n0 + ty) * 512 + k0 + tx] = f2b(s[tx][ty]);
    }
}

// ---------------------------------------------------------------------------
// QKV GEMM: 128x128 tiles, BK=64 via two 32-k planes (m97 staging).
// Epilogue: LDS repack, 16B stores; q,k scaled 0.125.  V written in TWO
// layouts: vR[slice][r][i][d] (residue-major, for attn_str — same 16x128B
// scatter cost as the old row-major ov store, but makes str's strided V read
// fully contiguous) and vF[slice][n/8][d][n%8] (for attn_band).
// ---------------------------------------------------------------------------
__global__ __launch_bounds__(256) void gemm_qkv(
    const ushort* __restrict__ A, const ushort* __restrict__ Bt,
    ushort* __restrict__ oq, ushort* __restrict__ ok, ushort* __restrict__ vR,
    ushort* __restrict__ vT)
{
    __shared__ ushort Sbuf[4 * 128 * 32];   // As[2] | Bs[2]
    ushort* As = Sbuf;
    ushort* Bs = Sbuf + 2 * 128 * 32;
    const int tid  = threadIdx.x;
    const int rowB = (blockIdx.x & 63) * 128;
    const int colB = (blockIdx.x >> 6) * 128;
    const int wave = tid >> 6, lane = tid & 63;
    const int wm = wave & 1, wn = wave >> 1;
    const int l15 = lane & 15, quad = lane >> 4;

    f32x4 acc[4][4] = {};

    for (int kt = 0; kt < 512; kt += 64) {
#pragma unroll
        for (int pl = 0; pl < 2; ++pl)
#pragma unroll
            for (int p = 0; p < 2; ++p) {
                const int c = p * 256 + tid;
                const int row = c >> 2, sc = (c & 3) * 8;
                async16(A  + (size_t)(rowB + row) * 512 + kt + pl * 32 + sc,
                        &As[pl * 4096 + c * 8]);
                async16(Bt + (size_t)(colB + row) * 512 + kt + pl * 32 + sc,
                        &Bs[pl * 4096 + c * 8]);
            }
        __syncthreads();

#pragma unroll
        for (int pl = 0; pl < 2; ++pl) {
            short8 af[4], bf[4];
#pragma unroll
            for (int mi = 0; mi < 4; ++mi)
                af[mi] = *(const short8*)&As[pl * 4096 +
                          (wm * 64 + mi * 16 + l15) * 32 + quad * 8];
#pragma unroll
            for (int ni = 0; ni < 4; ++ni)
                bf[ni] = *(const short8*)&Bs[pl * 4096 +
                          (wn * 64 + ni * 16 + l15) * 32 + quad * 8];
#pragma unroll
            for (int mi = 0; mi < 4; ++mi)
#pragma unroll
                for (int ni = 0; ni < 4; ++ni)
                    acc[mi][ni] = MFMA16(af[mi], bf[ni], acc[mi][ni]);
        }
        __syncthreads();
    }
    // Sbuf dead -> per-wave repack regions.

    ushort* T = Sbuf + wave * 2048;      // 16 rows x stride 72
    const int sec = colB >> 9;           // block-uniform
    const float s = (sec == 2) ? 1.0f : 0.125f;
    const int cb = (colB & 511) + wn * 64;
#pragma unroll
    for (int mi = 0; mi < 4; ++mi) {
#pragma unroll
        for (int ni = 0; ni < 4; ++ni)
#pragma unroll
            for (int r = 0; r < 4; ++r)
                T[(quad * 4 + r) * 72 + ni * 16 + l15] = f2b(acc[mi][ni][r] * s);
        if (sec != 2) {
            ushort* dst = (sec == 0) ? oq : ok;
#pragma unroll
            for (int u = 0; u < 2; ++u) {
                const int cid = lane * 2 + u;
                const int row = cid >> 3, ch = cid & 7;
                const int grow = rowB + wm * 64 + mi * 16 + row;
                *(short8*)&dst[(size_t)grow * HH + cb + ch * 8] =
                    *(const short8*)&T[row * 72 + ch * 8];
            }
        } else {
            const int hh = cb >> 6;
            const int bb = rowB >> 11;
            const int nn0 = (rowB & 2047) + wm * 64 + mi * 16;
            const int r0 = nn0 & 63, i0 = nn0 >> 6;   // 16 rows share i0
            // vR[slice][r][i][d]: 16 rows -> 16 x 128B lines at 4KB stride
            // (same transaction profile as the old row-major ov store).
            ushort* rbase = vR + ((size_t)(bb * HEADS + hh) * 2048) * 64;
#pragma unroll
            for (int u = 0; u < 2; ++u) {
                const int cid = lane * 2 + u;
                const int row = cid >> 3, ch = cid & 7;
                *(short8*)&rbase[((size_t)(r0 + row) * 32 + i0) * 64 + ch * 8] =
                    *(const short8*)&T[row * 72 + ch * 8];
            }
            // vF[slice][n/8][d=lane][n%8]: coalesced 1KB wave stores.
            ushort* vbase = vT +
                (((size_t)(bb * HEADS + hh) * 256 + (nn0 >> 3)) * 64) * 8;
#pragma unroll
            for (int u = 0; u < 2; ++u) {
                short8 val;
#pragma unroll
                for (int j = 0; j < 8; ++j) val[j] = T[(u * 8 + j) * 72 + lane];
                *(short8*)(vbase + ((size_t)(u * 64 + lane)) * 8) = val;
            }
        }
    }
}

// ---------------------------------------------------------------------------
// Unify GEMM: 128x64 tiles, BK=64 two-plane staging.  +bias, fp32 out.
// ---------------------------------------------------------------------------
__global__ __launch_bounds__(256) void gemm_unify(
    const ushort* __restrict__ A, const ushort* __restrict__ Bt,
    const float* __restrict__ bias, float* __restrict__ out)
{
    __shared__ ushort Sbuf[2 * 128 * 32 + 2 * 64 * 32];   // As[2] | Bs[2]
    ushort* As = Sbuf;
    ushort* Bs = Sbuf + 2 * 128 * 32;
    const int tid  = threadIdx.x;
    const int rowB = (blockIdx.x & 63) * 128;
    const int colB = (blockIdx.x >> 6) * 64;
    const int wave = tid >> 6, lane = tid & 63;
    const int wm = wave & 1, wn = wave >> 1;
    const int l15 = lane & 15, quad = lane >> 4;

    f32x4 acc[4][2] = {};

    for (int kt = 0; kt < 512; kt += 64) {
#pragma unroll
        for (int pl = 0; pl < 2; ++pl) {
#pragma unroll
            for (int p = 0; p < 2; ++p) {
                const int c = p * 256 + tid;
                const int row = c >> 2, sc = (c & 3) * 8;
                async16(A + (size_t)(rowB + row) * 512 + kt + pl * 32 + sc,
                        &As[pl * 4096 + c * 8]);
            }
            {
                const int row = tid >> 2, sc = (tid & 3) * 8;
                async16(Bt + (size_t)(colB + row) * 512 + kt + pl * 32 + sc,
                        &Bs[pl * 2048 + tid * 8]);
            }
        }
        __syncthreads();

#pragma unroll
        for (int pl = 0; pl < 2; ++pl) {
            short8 af[4], bf[2];
#pragma unroll
            for (int mi = 0; mi < 4; ++mi)
                af[mi] = *(const short8*)&As[pl * 4096 +
                          (wm * 64 + mi * 16 + l15) * 32 + quad * 8];
#pragma unroll
            for (int ni = 0; ni < 2; ++ni)
                bf[ni] = *(const short8*)&Bs[pl * 2048 +
                          (wn * 32 + ni * 16 + l15) * 32 + quad * 8];
#pragma unroll
            for (int mi = 0; mi < 4; ++mi)
#pragma unroll
                for (int ni = 0; ni < 2; ++ni)
                    acc[mi][ni] = MFMA16(af[mi], bf[ni], acc[mi][ni]);
        }
        __syncthreads();
    }
    // Sbuf dead -> per-wave fp32 repack: 16 rows x stride 36 floats.

    float* Tf = (float*)Sbuf + wave * (16 * 36);
    float bcol[2];
#pragma unroll
    for (int ni = 0; ni < 2; ++ni)
        bcol[ni] = bias[colB + wn * 32 + ni * 16 + l15];
#pragma unroll
    for (int mi = 0; mi < 4; ++mi) {
#pragma unroll
        for (int ni = 0; ni < 2; ++ni)
#pragma unroll
            for (int r = 0; r < 4; ++r)
                Tf[(quad * 4 + r) * 36 + ni * 16 + l15] =
                    acc[mi][ni][r] + bcol[ni];
#pragma unroll
        for (int u = 0; u < 2; ++u) {
            const int cid = lane * 2 + u;
            const int row = cid >> 3, ch = cid & 7;
            *(float4*)&out[(size_t)(rowB + wm * 64 + mi * 16 + row) * EMB +
                           colB + wn * 32 + ch * 4] =
                *(const float4*)&Tf[row * 36 + ch * 4];
        }
    }
}

// ---------------------------------------------------------------------------
// Kernel B: strided attention in RESIDUE space.  V read from vR[slice][r][i][d]
// — 1KB contiguous per load group (was 32 scattered 128B lines).
// ---------------------------------------------------------------------------
__global__ __launch_bounds__(64) void attn_str(
    const ushort* __restrict__ q, const ushort* __restrict__ k,
    const ushort* __restrict__ vR, ushort* __restrict__ obn,
    float* __restrict__ mbuf, float* __restrict__ sbuf)
{
    const int slice = blockIdx.x & 31;     // h + 8*b
    const int r     = blockIdx.x >> 5;     // residue 0..63
    const int h = slice & 7, b = slice >> 3;
    const int lane = threadIdx.x, l15 = lane & 15, quad = lane >> 4;
    const ptrdiff_t rowb = (ptrdiff_t)b * NSEQ;
    const int hb = h * HID;

    __shared__ union {
        struct { ushort Ps[32][40]; ushort Vt[64][40]; } s;
        float Ot[32][66];
    } U;

    {
        const int dg = lane & 7, g = lane >> 3;
        const ushort* vs = vR + ((size_t)(b * HEADS + h) * 2048 + (size_t)r * 32) * 64;
#pragma unroll
        for (int p = 0; p < 4; ++p) {
            const int i = p * 8 + g;
            const short8 vv = *(const short8*)(vs + (size_t)i * 64 + dg * 8);
#pragma unroll
            for (int e = 0; e < 8; ++e) {
                const int m = (e + dg) & 7;
                U.s.Vt[dg * 8 + m][i] = (ushort)vv[m];
            }
        }
    }
    { ushort4 z = {0, 0, 0, 0}; *(ushort4*)&U.s.Ps[l15][16 + quad * 4] = z; }

    short8 aq[2][2], bk[2][2];
#pragma unroll
    for (int t = 0; t < 2; ++t) {
        const ushort* p = q + (rowb + r + 64 * (t * 16 + l15)) * 512 + hb + quad * 8;
        aq[t][0] = *(const short8*)p;
        aq[t][1] = *(const short8*)(p + 32);
        const ushort* pk = k + (rowb + r + 64 * (t * 16 + l15)) * 512 + hb + quad * 8;
        bk[t][0] = *(const short8*)pk;
        bk[t][1] = *(const short8*)(pk + 32);
    }
    f32x4 s00 = {}, s10 = {}, s11 = {};
    s00 = MFMA16(aq[0][0], bk[0][0], s00); s00 = MFMA16(aq[0][1], bk[0][1], s00);
    s10 = MFMA16(aq[1][0], bk[0][0], s10); s10 = MFMA16(aq[1][1], bk[0][1], s10);
    s11 = MFMA16(aq[1][0], bk[1][0], s11); s11 = MFMA16(aq[1][1], bk[1][1], s11);

    float rsB[2][4];
#pragma unroll
    for (int t = 0; t < 2; ++t)
#pragma unroll
        for (int rg = 0; rg < 4; ++rg) {
            const int i = t * 16 + quad * 4 + rg;
            float v0 = (t == 0) ? s00[rg] : s10[rg];
            float v1 = (t == 1) ? s11[rg] : -1e30f;
            if (l15 > i - 2) v0 = -1e30f;
            if (t == 1 && 16 + l15 > i - 2) v1 = -1e30f;
            float mx = fmaxf(v0, v1);
            mx = fmaxf(mx, __shfl_xor(mx, 1)); mx = fmaxf(mx, __shfl_xor(mx, 2));
            mx = fmaxf(mx, __shfl_xor(mx, 4)); mx = fmaxf(mx, __shfl_xor(mx, 8));
            const float e0 = __expf(v0 - mx);
            const float e1 = (t == 1) ? __expf(v1 - mx) : 0.f;
            float sum = e0 + e1;
            sum += __shfl_xor(sum, 1); sum += __shfl_xor(sum, 2);
            sum += __shfl_xor(sum, 4); sum += __shfl_xor(sum, 8);
            U.s.Ps[i][l15] = f2b(e0);
            if (t == 1) U.s.Ps[i][16 + l15] = f2b(e1);
            rsB[t][rg] = 1.0f / sum;
            if (l15 == 0 && i >= 2) {
                mbuf[(size_t)slice * NSEQ + r + 64 * i] = mx;
                sbuf[(size_t)slice * NSEQ + r + 64 * i] = sum;
            }
        }

    short8 ap[2], bp[4];
#pragma unroll
    for (int t = 0; t < 2; ++t)
        ap[t] = *(const short8*)&U.s.Ps[t * 16 + l15][quad * 8];
#pragma unroll
    for (int nt = 0; nt < 4; ++nt)
        bp[nt] = *(const short8*)&U.s.Vt[nt * 16 + l15][quad * 8];
    f32x4 O[2][4] = {};
#pragma unroll
    for (int t = 0; t < 2; ++t)
#pragma unroll
        for (int nt = 0; nt < 4; ++nt)
            O[t][nt] = MFMA16(ap[t], bp[nt], O[t][nt]);

#pragma unroll
    for (int t = 0; t < 2; ++t)
#pragma unroll
        for (int nt = 0; nt < 4; ++nt)
#pragma unroll
            for (int rg = 0; rg < 4; ++rg)
                U.Ot[t * 16 + quad * 4 + rg][nt * 16 + l15] = O[t][nt][rg] * rsB[t][rg];
    for (int i = 2; i < 32; ++i)
        obn[(rowb + r + 64 * i) * 512 + hb + lane] = f2b(U.Ot[i][lane]);
}

// ---------------------------------------------------------------------------
// Kernel A: local-band attention + flash-merge, 32 queries/wave.
// ---------------------------------------------------------------------------
struct __align__(16) WaveWS {
    union { ushort Ps[32][104]; float Ot[32][66]; } u;   // 104: 208B stride, 2-way
    float ca[32], cb[32];
};

__global__ __launch_bounds__(64) void attn_band(
    const ushort* __restrict__ q, const ushort* __restrict__ k,
    const ushort* __restrict__ vT, const ushort* __restrict__ obn,
    const float* __restrict__ mbuf, const float* __restrict__ sbuf,
    ushort* __restrict__ o)
{
    const int slice = blockIdx.x & 31;
    const int qidx  = blockIdx.x >> 5;
    const int h = slice & 7, b = slice >> 3;
    const int lane = threadIdx.x;
    const int l15 = lane & 15, quad = lane >> 4;
    const int qw = qidx * 32;
    const int band0 = qw - 64;
    const bool merge = (qw >= 128);

    __shared__ WaveWS S;
    const ptrdiff_t rowb = (ptrdiff_t)b * NSEQ;
    const int hb = h * HID;

    short8 afq[2][2];
#pragma unroll
    for (int t = 0; t < 2; ++t) {
        const ushort* qp = q + (rowb + qw + t * 16 + l15) * 512 + hb + quad * 8;
        afq[t][0] = *(const short8*)qp;
        afq[t][1] = *(const short8*)(qp + 32);
    }

    // QK^T over the 96-col band: t=0 uses cols [0,80), t=1 uses [16,96).
    f32x4 accA[5], accB[5];
#pragma unroll
    for (int i = 0; i < 5; ++i) {
        accA[i] = (f32x4){0.f, 0.f, 0.f, 0.f};
        accB[i] = (f32x4){0.f, 0.f, 0.f, 0.f};
    }
#pragma unroll
    for (int kt = 0; kt < 6; ++kt) {
        const ushort* kp = k + (rowb + band0 + kt * 16 + l15) * 512 + hb + quad * 8;
        const short8 b0 = *(const short8*)kp;
        const short8 b1 = *(const short8*)(kp + 32);
        if (kt < 5) {
            accA[kt] = MFMA16(afq[0][0], b0, accA[kt]);
            accA[kt] = MFMA16(afq[0][1], b1, accA[kt]);
        }
        if (kt > 0) {
            accB[kt - 1] = MFMA16(afq[1][0], b0, accB[kt - 1]);
            accB[kt - 1] = MFMA16(afq[1][1], b1, accB[kt - 1]);
        }
    }

#pragma unroll
    for (int t = 0; t < 2; ++t)
#pragma unroll
        for (int rg = 0; rg < 4; ++rg) {
            const int row16 = quad * 4 + rg;
            const int i = t * 16 + row16;
            float pm[6], mx = -1e30f;
#pragma unroll
            for (int kt = 0; kt < 6; ++kt) {
                const int col = kt * 16 + l15;
                float val = -1e30f;
                if (t == 0) { if (kt < 5) val = accA[kt][rg]; }
                else        { if (kt > 0) val = accB[kt - 1][rg]; }
                const bool okm = (col >= i) && (col <= i + 64) && (band0 + col >= 0);
                pm[kt] = okm ? val : -1e30f;
                mx = fmaxf(mx, pm[kt]);
            }
            mx = fmaxf(mx, __shfl_xor(mx, 1)); mx = fmaxf(mx, __shfl_xor(mx, 2));
            mx = fmaxf(mx, __shfl_xor(mx, 4)); mx = fmaxf(mx, __shfl_xor(mx, 8));
            float sum = 0.f;
#pragma unroll
            for (int kt = 0; kt < 6; ++kt) {
                const float pv = __expf(pm[kt] - mx);
                sum += pv;
                S.u.Ps[i][kt * 16 + l15] = f2b(pv);
            }
            sum += __shfl_xor(sum, 1); sum += __shfl_xor(sum, 2);
            sum += __shfl_xor(sum, 4); sum += __shfl_xor(sum, 8);
            if (l15 == 0) {
                if (merge) {
                    const float mB = mbuf[(size_t)slice * NSEQ + qw + i];
                    const float sB = sbuf[(size_t)slice * NSEQ + qw + i];
                    const float m  = fmaxf(mx, mB);
                    const float eA = __expf(mx - m), eB = __expf(mB - m);
                    const float denom = sum * eA + sB * eB;
                    S.ca[i] = eA / denom;
                    S.cb[i] = sB * eB / denom;
                } else {
                    S.ca[i] = 1.0f / sum;
                    S.cb[i] = 0.f;
                }
            }
        }

    f32x4 O[2][4] = {};
    const ushort* vtb = vT + (size_t)slice * (256 * 64 * 8);
#pragma unroll
    for (int ks = 0; ks < 3; ++ks) {
        const short8 ap0 = *(const short8*)&S.u.Ps[l15][ks * 32 + quad * 8];
        const short8 ap1 = *(const short8*)&S.u.Ps[16 + l15][ks * 32 + quad * 8];
        const int nb = (band0 >> 3) + ks * 4 + quad;   // may be negative: P==0 there
#pragma unroll
        for (int nt = 0; nt < 4; ++nt) {
            const short8 bp = *(const short8*)(
                vtb + ((ptrdiff_t)nb * 64 + nt * 16 + l15) * 8);
            O[0][nt] = MFMA16(ap0, bp, O[0][nt]);
            O[1][nt] = MFMA16(ap1, bp, O[1][nt]);
        }
    }

#pragma unroll
    for (int t = 0; t < 2; ++t)
#pragma unroll
        for (int nt = 0; nt < 4; ++nt)
#pragma unroll
            for (int rg = 0; rg < 4; ++rg)
                S.u.Ot[t * 16 + quad * 4 + rg][nt * 16 + l15] = O[t][nt][rg];

    if (merge) {
#pragma unroll 4
        for (int i2 = 0; i2 < 32; ++i2) {
            const ptrdiff_t off = (rowb + qw + i2) * 512 + hb + lane;
            const float val = S.u.Ot[i2][lane] * S.ca[i2] + b2f(obn[off]) * S.cb[i2];
            o[off] = f2b(val);
        }
    } else {
#pragma unroll 4
        for (int i2 = 0; i2 < 32; ++i2) {
            const ptrdiff_t off = (rowb + qw + i2) * 512 + hb + lane;
            o[off] = f2b(S.u.Ot[i2][lane] * S.ca[i2]);
        }
    }
}

// ---------------------------------------------------------------------------
extern "C" void kernel_launch(void* const* d_in, const int* in_sizes, int n_in,
                              void* d_out, int out_size, void* d_ws, size_t ws_size,
                              hipStream_t stream)
{
    // dict order: x, w_keys, w_queries, w_values, w_unify, b_unify (fp32)
    const float* x  = (const float*)d_in[0];
    const float* wk = (const float*)d_in[1];
    const float* wq = (const float*)d_in[2];
    const float* wv = (const float*)d_in[3];
    const float* wu = (const float*)d_in[4];
    const float* bu = (const float*)d_in[5];
    float* out = (float*)d_out;

    // ws: xb 8M | wbt 1.5M | wubt .5M | ob 8M | qb 8M | kb 8M | vF 8M | vR 8M
    //     | obn 8M | mbuf .25M | sbuf .25M
    ushort* xb   = (ushort*)d_ws;
    ushort* wbt  = xb   + (size_t)ROWS * EMB;
    ushort* wubt = wbt  + (size_t)1536 * 512;
    ushort* ob   = wubt + (size_t)512 * 512;
    ushort* qbuf = ob   + (size_t)ROWS * HH;
    ushort* kbuf = qbuf + (size_t)ROWS * HH;
    ushort* vTb  = kbuf + (size_t)ROWS * HH;
    ushort* vRb  = vTb  + (size_t)ROWS * HH;
    ushort* obn  = vRb  + (size_t)ROWS * HH;
    float*  mbuf = (float*)(obn + (size_t)ROWS * HH);
    float*  sbuf = mbuf + (size_t)32 * NSEQ;

    prep<<<8192, 256, 0, stream>>>(x, wq, wk, wv, wu, xb, wbt, wubt);
    gemm_qkv<<<12 * 64, 256, 0, stream>>>(xb, wbt, qbuf, kbuf, vRb, vTb);
    attn_str<<<64 * 32, 64, 0, stream>>>(qbuf, kbuf, vRb, obn, mbuf, sbuf);
    attn_band<<<64 * 32, 64, 0, stream>>>(qbuf, kbuf, vTb, obn, mbuf, sbuf, ob);
    gemm_unify<<<8 * 64, 256, 0, stream>>>(ob, wubt, bu, out);
}